// Round 6
// baseline (176.815 us; speedup 1.0000x reference)
//
#include <hip/hip_runtime.h>
#include <math.h>

// Problem constants (fixed by the reference).
#define kB 2
#define kS 2048
#define kD 1024
#define kH 16
#define kDk 64
#define kM (kB * kS)  // 4096 rows of x
#define kNT (kD / 64) // 16 K-tiles of BK=64
// log2(10000)
#define kLog2Theta 13.287712379549449
// 0.125 (1/sqrt(dk)) * log2(e): folded into stored Q; softmax in exp2 space
#define C_SCALE 0.18033688011112042f

typedef __attribute__((ext_vector_type(4))) float f32x4;
typedef __attribute__((ext_vector_type(16))) float f32x16;
typedef __attribute__((ext_vector_type(8))) __bf16 bf16x8;

__device__ __forceinline__ ushort f2bf(float f) {
  uint u = __float_as_uint(f);
  return (ushort)((u + 0x7fffu + ((u >> 16) & 1u)) >> 16);  // RNE
}
__device__ __forceinline__ uint cvt_pk_bf16(float lo, float hi) {
  uint r;
  asm("v_cvt_pk_bf16_f32 %0, %1, %2" : "=v"(r) : "v"(lo), "v"(hi));
  return r;
}

typedef __attribute__((address_space(1))) void gvoid;
typedef __attribute__((address_space(3))) void lvoid;
__device__ __forceinline__ void load_lds16(const void* g, void* l) {
  __builtin_amdgcn_global_load_lds((gvoid*)g, (lvoid*)l, 16, 0, 0);
}

// ---------------------------------------------------------------------------
// RoPE cos/sin table: tab[s*32+p] = {cos, sin}(s * theta^(-p/32)). f64 trig.
// ---------------------------------------------------------------------------
__global__ __launch_bounds__(256) void rope_table_kernel(float2* __restrict__ tab) {
  const int i = blockIdx.x * 256 + threadIdx.x;  // 65536 entries
  const int s = i >> 5, p = i & 31;
  const double ang = (double)s * exp2(-(double)p * (kLog2Theta / 32.0));
  tab[i] = make_float2((float)cos(ang), (float)sin(ang));
}

// ---------------------------------------------------------------------------
// All three f32 -> bf16 casts in one launch (RNE), float4 per thread.
// ---------------------------------------------------------------------------
__global__ __launch_bounds__(256) void cast_all_kernel(
    const float* __restrict__ x, const float* __restrict__ wq,
    const float* __restrict__ wo, ushort* __restrict__ xb,
    ushort* __restrict__ wqb, ushort* __restrict__ wob) {
  const int i = blockIdx.x * 256 + threadIdx.x;
  const float* src;
  ushort* dst;
  int off;
  if (i < 1048576) {
    src = x; dst = xb; off = i;
  } else if (i < 1048576 + 786432) {
    src = wq; dst = wqb; off = i - 1048576;
  } else {
    src = wo; dst = wob; off = i - 1835008;
  }
  const float4 v = reinterpret_cast<const float4*>(src)[off];
  ushort4 o;
  o.x = f2bf(v.x); o.y = f2bf(v.y); o.z = f2bf(v.z); o.w = f2bf(v.w);
  reinterpret_cast<ushort4*>(dst)[off] = o;
}

// ---------------------------------------------------------------------------
// V (B,H,S,dk) -> Vt (B,H,dk,S), LDS-tiled 64x64 transpose.
// ---------------------------------------------------------------------------
__global__ __launch_bounds__(256) void vtrans_kernel(
    const ushort* __restrict__ v, ushort* __restrict__ vt) {
  __shared__ ushort T[64 * 66];
  const int bh = blockIdx.y, st = blockIdx.x;
  const int tid = threadIdx.x;
  const ushort* vp = v + ((size_t)bh * kS + st * 64) * kDk;
#pragma unroll
  for (int u = 0; u < 2; ++u) {
    const int idx = u * 256 + tid;
    const int r = idx >> 3, c = (idx & 7) << 3;
    const uint4 d4 = *reinterpret_cast<const uint4*>(&vp[r * 64 + c]);
    uint* dst = reinterpret_cast<uint*>(&T[r * 66 + c]);
    dst[0] = d4.x; dst[1] = d4.y; dst[2] = d4.z; dst[3] = d4.w;
  }
  __syncthreads();
  const int d = tid >> 2, seg = tid & 3;
  ushort tmp[16];
#pragma unroll
  for (int j = 0; j < 16; ++j) tmp[j] = T[(seg * 16 + j) * 66 + d];
  ushort* dst = vt + ((size_t)bh * kDk + d) * kS + st * 64 + seg * 16;
  *reinterpret_cast<uint4*>(dst) = *reinterpret_cast<uint4*>(tmp);
  *reinterpret_cast<uint4*>(dst + 8) = *reinterpret_cast<uint4*>(tmp + 8);
}

// ---------------------------------------------------------------------------
// 256x256 8-wave counted-vmcnt GEMM mainloop (m201-template port).
// C[256x256] = A[256xK] * B[256xK]^T, bf16 K-major inputs.
// 512 thr = 8 waves (2M x 4N), per-wave output 128x64 (8x4 frags of 16x16).
// LDS: 2 K-tile buffers x (A 256x64 + B 256x64) bf16 = 128 KB.
// Per K-tile: 4 quadrant-phases {12 swizzled ds_read_b128 | stage-issue ->
// s_barrier -> lgkmcnt(0) -> setprio(1) 16 MFMA setprio(0) -> s_barrier}.
// All 8 staging loads of tile t+1 issue at phase 0; single vmcnt(0) at end of
// phase 3 (~3 phases after issue — never waits on just-issued loads).
// LDS slot-swizzle slot ^= (row&7): inverse-swizzled global source + swizzled
// frag reads (both-sides, rule #21) -> conflict-free ds_read_b128.
// ---------------------------------------------------------------------------
__device__ __forceinline__ void gemm256_mainloop(
    const ushort* __restrict__ A, const ushort* __restrict__ B,
    int m0, int n0, int tid,
    ushort* As0, ushort* Bs0, ushort* As1, ushort* Bs1,
    f32x4 (&acc)[8][4]) {
  const int lane = tid & 63;
  const int wmi = (tid >> 6) >> 2;   // 0..1 (M wave row)
  const int wni = (tid >> 6) & 3;    // 0..3 (N wave col)
  const int fr = lane & 15, fq = lane >> 4;

  // Stage one full K-tile (A 256x64 + B 256x64) with inverse-swizzled source.
  auto stage_tile = [&](int k0, ushort* Ad, ushort* Bd) {
#pragma unroll
    for (int half = 0; half < 2; ++half)
#pragma unroll
      for (int u = 0; u < 2; ++u) {
        const int c = u * 512 + tid;
        const int r = c >> 3, sl = c & 7;
        const int gcol = k0 + ((sl ^ (r & 7)) << 3);
        const int loff = ((half * 128 + r) << 6) + (sl << 3);
        load_lds16(&A[(size_t)(m0 + half * 128 + r) * kD + gcol], &Ad[loff]);
        load_lds16(&B[(size_t)(n0 + half * 128 + r) * kD + gcol], &Bd[loff]);
      }
  };
  // Swizzled fragment read: logical K-slot (kk*4+fq) at physical ^ (row&7).
  auto frag = [&](const ushort* S, int row, int kk) -> bf16x8 {
    const int off = ((kk << 5) + (fq << 3)) ^ ((fr & 7) << 3);
    return *reinterpret_cast<const bf16x8*>(&S[(row << 6) + off]);
  };

  stage_tile(0, As0, Bs0);
  asm volatile("s_waitcnt vmcnt(0)" ::: "memory");
  __builtin_amdgcn_s_barrier();

  auto tile = [&](int kt, const ushort* cA, const ushort* cB,
                  ushort* nA, ushort* nB) {
#pragma unroll
    for (int p = 0; p < 4; ++p) {
      const int iset = (p & 1) << 2, jset = (p >> 1) << 1;
      bf16x8 af[4][2], bfv[2][2];
#pragma unroll
      for (int i2 = 0; i2 < 4; ++i2)
#pragma unroll
        for (int kk = 0; kk < 2; ++kk)
          af[i2][kk] = frag(cA, (wmi << 7) + (iset + i2) * 16 + fr, kk);
#pragma unroll
      for (int j2 = 0; j2 < 2; ++j2)
#pragma unroll
        for (int kk = 0; kk < 2; ++kk)
          bfv[j2][kk] = frag(cB, (wni << 6) + (jset + j2) * 16 + fr, kk);
      if (p == 0 && kt + 1 < kNT) stage_tile((kt + 1) << 6, nA, nB);
      __builtin_amdgcn_s_barrier();
      asm volatile("s_waitcnt lgkmcnt(0)" ::: "memory");
      __builtin_amdgcn_sched_barrier(0);
      __builtin_amdgcn_s_setprio(1);
#pragma unroll
      for (int i2 = 0; i2 < 4; ++i2)
#pragma unroll
        for (int j2 = 0; j2 < 2; ++j2)
#pragma unroll
          for (int kk = 0; kk < 2; ++kk)
            acc[iset + i2][jset + j2] = __builtin_amdgcn_mfma_f32_16x16x32_bf16(
                af[i2][kk], bfv[j2][kk], acc[iset + i2][jset + j2], 0, 0, 0);
      __builtin_amdgcn_s_setprio(0);
      if (p == 3) asm volatile("s_waitcnt vmcnt(0)" ::: "memory");
      __builtin_amdgcn_s_barrier();
    }
  };

  for (int kt = 0; kt < kNT; kt += 2) {
    tile(kt, As0, Bs0, As1, Bs1);
    tile(kt + 1, As1, Bs1, As0, Bs0);
  }
}

// ---------------------------------------------------------------------------
// QKV projection (256² 8-phase) with fused RoPE epilogue. Q,K,V bf16
// (B,H,S,dk); Q pre-scaled by C_SCALE.
// ---------------------------------------------------------------------------
__global__ __launch_bounds__(512, 2) void qkv_mfma_kernel(
    const ushort* __restrict__ xb, const ushort* __restrict__ wqb,
    const float2* __restrict__ tab,
    ushort* __restrict__ q, ushort* __restrict__ k, ushort* __restrict__ v) {
  __shared__ ushort As0[256 * 64], Bs0[256 * 64];
  __shared__ ushort As1[256 * 64], Bs1[256 * 64];
  const int tid = threadIdx.x;
  const int m0 = blockIdx.y << 8, n0 = blockIdx.x << 8;
  f32x4 acc[8][4];
#pragma unroll
  for (int i = 0; i < 8; ++i)
#pragma unroll
    for (int j = 0; j < 4; ++j) acc[i][j] = {0.f, 0.f, 0.f, 0.f};

  gemm256_mainloop(xb, wqb, m0, n0, tid, As0, Bs0, As1, Bs1, acc);

  const int lane = tid & 63;
  const int wmi = (tid >> 6) >> 2, wni = (tid >> 6) & 3;
  const int fr = lane & 15, fq = lane >> 4;
  const int t = n0 >> 10;  // 0=Q 1=K 2=V (block-uniform: 256 | 1024)
  ushort* dst = (t == 0) ? q : (t == 1) ? k : v;

#pragma unroll
  for (int i = 0; i < 8; ++i) {
    const int mbase = m0 + (wmi << 7) + i * 16 + fq * 4;
#pragma unroll
    for (int j = 0; j < 4; ++j) {
      const int n = n0 + (wni << 6) + j * 16 + fr;
      const int h = (n >> 6) & 15, d = n & 63;
#pragma unroll
      for (int r = 0; r < 4; ++r) {
        const int m = mbase + r;
        const int b = m >> 11, s = m & (kS - 1);
        float val = acc[i][j][r];
        if (t < 2) {  // RoPE: pair exchange with lane^1 (cols d, d^1)
          const float2 cs = tab[(s << 5) + (d >> 1)];
          const float partner = __shfl_xor(val, 1);
          val = (d & 1) ? (partner * cs.y + val * cs.x)
                        : (val * cs.x - partner * cs.y);
        }
        if (t == 0) val *= C_SCALE;  // fold softmax scale into Q
        dst[(((size_t)((b << 4) + h) << 11) + s) * kDk + d] = f2bf(val);
      }
    }
  }
}

// ---------------------------------------------------------------------------
// Output projection (256² 8-phase), f32 store to d_out.
// ---------------------------------------------------------------------------
__global__ __launch_bounds__(512, 2) void proj_mfma_kernel(
    const ushort* __restrict__ ab, const ushort* __restrict__ wob,
    float* __restrict__ out) {
  __shared__ ushort As0[256 * 64], Bs0[256 * 64];
  __shared__ ushort As1[256 * 64], Bs1[256 * 64];
  const int tid = threadIdx.x;
  const int m0 = blockIdx.y << 8, n0 = blockIdx.x << 8;
  f32x4 acc[8][4];
#pragma unroll
  for (int i = 0; i < 8; ++i)
#pragma unroll
    for (int j = 0; j < 4; ++j) acc[i][j] = {0.f, 0.f, 0.f, 0.f};

  gemm256_mainloop(ab, wob, m0, n0, tid, As0, Bs0, As1, Bs1, acc);

  const int lane = tid & 63;
  const int wmi = (tid >> 6) >> 2, wni = (tid >> 6) & 3;
  const int fr = lane & 15, fq = lane >> 4;
#pragma unroll
  for (int i = 0; i < 8; ++i)
#pragma unroll
    for (int j = 0; j < 4; ++j)
#pragma unroll
      for (int r = 0; r < 4; ++r)
        out[(size_t)(m0 + (wmi << 7) + i * 16 + fq * 4 + r) * kD +
            n0 + (wni << 6) + j * 16 + fr] = acc[i][j][r];
}

// ---------------------------------------------------------------------------
// Causal flash attention, bf16 MFMA 32x32x16, swapped operands, KVBLK=128,
// double-buffered LDS (64KB), static-max softmax (scores are O(1e-2): fixed
// max is exact; no rescale, no max tracking).
// ---------------------------------------------------------------------------
__global__ __launch_bounds__(256) void attn_mfma_kernel(
    const ushort* __restrict__ q, const ushort* __restrict__ k,
    const ushort* __restrict__ vt, ushort* __restrict__ ob) {
  __shared__ ushort smem[32768];  // 64KB: buf{0,1} x (Ks[128][64] | Vts[64][128])
  const int tid = threadIdx.x;
  const int lane = tid & 63;
  const int wq = tid >> 6;             // wave 0..3
  const int l5 = lane >> 5;
  const int ln = lane & 31;            // q column owned by this lane
  const int swz = (ln & 7) << 4;       // LDS byte swizzle for frag reads

  // Balanced (qi, bh) mapping: grp<8 -> qi 15..8, grp>=8 -> qi 0..7.
  const int idx = blockIdx.x;
  const int grp = idx >> 5, bh = idx & 31;
  const int qi = (grp < 8) ? (15 - grp) : (grp - 8);
  const int qb = qi << 7;
  const int nt = qi + 1;               // 128-key tiles

  const ushort* qp = q + (size_t)bh * kS * kDk;
  const ushort* kp = k + (size_t)bh * kS * kDk;
  const ushort* vp = vt + (size_t)bh * kDk * kS;  // [d][s]

  // Q fragments (B-operand, persist): dk = kk*16 + l5*8 + j. Q pre-scaled.
  bf16x8 bq[4];
#pragma unroll
  for (int kk = 0; kk < 4; ++kk)
    bq[kk] = *reinterpret_cast<const bf16x8*>(
        &qp[(size_t)(qb + wq * 32 + ln) * kDk + kk * 16 + l5 * 8]);

  f32x16 acc_o[2];
#pragma unroll
  for (int db = 0; db < 2; ++db)
#pragma unroll
    for (int r = 0; r < 16; ++r) acc_o[db][r] = 0.f;
  float l_run = 0.f;

  auto stage = [&](int kt, int buf) {
    ushort* Kd = smem + buf * 16384;
    ushort* Vd = Kd + 8192;
#pragma unroll
    for (int u = 0; u < 4; ++u) {
      const int c = u * 256 + tid;
      {
        const int r = c >> 3, sl = c & 7;
        load_lds16(&kp[(size_t)(kt * 128 + r) * kDk + ((sl ^ (r & 7)) << 3)],
                   &Kd[c << 3]);
      }
      {
        const int r = c >> 4, sl = c & 15;
        load_lds16(&vp[(size_t)r * kS + kt * 128 + ((sl ^ (r & 7)) << 3)],
                   &Vd[c << 3]);
      }
    }
  };

  stage(0, 0);

  for (int kt = 0; kt < nt; ++kt) {
    const int cur = kt & 1;
    __syncthreads();                   // buf[cur] ready (vmcnt drained here)
    if (kt + 1 < nt) stage(kt + 1, cur ^ 1);  // prefetch flies under compute

    const char* KsB = reinterpret_cast<const char*>(smem + cur * 16384);
    const char* VtsB = KsB + 16384;

    // ---- QK^T: 4 key-blocks of 32 ----
    f32x16 accs[4];
    __builtin_amdgcn_s_setprio(1);
#pragma unroll
    for (int cb = 0; cb < 4; ++cb) {
#pragma unroll
      for (int r = 0; r < 16; ++r) accs[cb][r] = 0.f;
#pragma unroll
      for (int kk = 0; kk < 4; ++kk) {
        const bf16x8 av = *reinterpret_cast<const bf16x8*>(
            KsB + (cb * 32 + ln) * 128 + ((kk * 32 + l5 * 16) ^ swz));
        accs[cb] = __builtin_amdgcn_mfma_f32_32x32x16_bf16(av, bq[kk], accs[cb], 0, 0, 0);
      }
    }
    __builtin_amdgcn_s_setprio(0);

    // ---- causal mask (diagonal tile only) ----
    if (kt == qi) {
      const int lim = (wq << 5) + ln;  // qrow - qb
#pragma unroll
      for (int cb = 0; cb < 4; ++cb)
#pragma unroll
        for (int r = 0; r < 16; ++r) {
          const int key = cb * 32 + (r & 3) + 8 * (r >> 2) + 4 * l5;
          if (key > lim) accs[cb][r] = -INFINITY;
        }
    }

    // ---- static-max softmax: p = exp2(s), accumulate l ----
    uint c8[4][8];
    float lsum = 0.f;
#pragma unroll
    for (int cb = 0; cb < 4; ++cb) {
      float s0 = 0.f, s1 = 0.f, s2 = 0.f, s3 = 0.f;
      float p[16];
#pragma unroll
      for (int r = 0; r < 16; ++r) {
        p[r] = exp2f(accs[cb][r]);
        if ((r & 3) == 0) s0 += p[r];
        else if ((r & 3) == 1) s1 += p[r];
        else if ((r & 3) == 2) s2 += p[r];
        else s3 += p[r];
      }
      lsum += (s0 + s1) + (s2 + s3);
#pragma unroll
      for (int t = 0; t < 8; ++t)
        c8[cb][t] = cvt_pk_bf16(p[2 * t], p[2 * t + 1]);
    }
    l_run += lsum;

    // ---- PV: for each 16-key slab, build P B-frag and MFMA ----
    __builtin_amdgcn_s_setprio(1);
#pragma unroll
    for (int kb = 0; kb < 8; ++kb) {
      const int cb = kb >> 1, base = (kb & 1) * 4;
      const uint a0 = c8[cb][base + 0], a1 = c8[cb][base + 1];
      const uint b0 = c8[cb][base + 2], b1 = c8[cb][base + 3];
      const uint sa0 = (uint)__shfl_xor((int)a0, 32);
      const uint sa1 = (uint)__shfl_xor((int)a1, 32);
      const uint sb0 = (uint)__shfl_xor((int)b0, 32);
      const uint sb1 = (uint)__shfl_xor((int)b1, 32);
      uint4 dw;
      dw.x = l5 ? sb0 : a0;
      dw.y = l5 ? sb1 : a1;
      dw.z = l5 ? b0 : sa0;
      dw.w = l5 ? b1 : sa1;
      const bf16x8 pa = *reinterpret_cast<const bf16x8*>(&dw);
#pragma unroll
      for (int db = 0; db < 2; ++db) {
        const bf16x8 av = *reinterpret_cast<const bf16x8*>(
            VtsB + (db * 32 + ln) * 256 + ((kb * 32 + l5 * 16) ^ swz));
        acc_o[db] = __builtin_amdgcn_mfma_f32_32x32x16_bf16(av, pa, acc_o[db], 0, 0, 0);
      }
    }
    __builtin_amdgcn_s_setprio(0);
  }

  // ---- combine the two half-wave l partials, normalize, store ----
  const float l_tot = l_run + __shfl_xor(l_run, 32);
  const float linv = 1.f / l_tot;

  __syncthreads();                     // all waves done with K/Vt buffers
  char* OsB = reinterpret_cast<char*>(smem);  // Os: [128 q][64 d], swizzled
  const int orow = wq * 32 + ln;
#pragma unroll
  for (int db = 0; db < 2; ++db)
#pragma unroll
    for (int t = 0; t < 8; ++t) {
      const int reg = 2 * t;
      const int d = db * 32 + (reg & 3) + 8 * (reg >> 2) + 4 * l5;
      const uint pk2 = cvt_pk_bf16(acc_o[db][reg] * linv, acc_o[db][reg + 1] * linv);
      *reinterpret_cast<uint*>(OsB + orow * 128 + ((d * 2) ^ swz)) = pk2;
    }
  __syncthreads();
  const int b = bh >> 4, h = bh & 15;
  const int qrw = tid >> 1, half = tid & 1;
  ushort* orow_g = ob + ((size_t)(b * kS + qb + qrw)) * kD + h * kDk + half * 32;
#pragma unroll
  for (int sl = 0; sl < 4; ++sl) {
    const uint4 vdat = *reinterpret_cast<const uint4*>(
        OsB + qrw * 128 + ((half * 64 + sl * 16) ^ ((qrw & 7) << 4)));
    *reinterpret_cast<uint4*>(orow_g + sl * 8) = vdat;
  }
}

// ---------------------------------------------------------------------------
// Workspace (bytes from d_ws base), total 49 MB:
//   qb 0..8M, kb 8..16M, vb 16..24M (bf16, (B,H,S,dk))
//   xb 24..32M (x bf16; aliased as attnb after QKV GEMM)
//   wqb 32..38M, wob 38..40M, tab 40..40.5M, vtb 41..49M (Vt (B,H,dk,S))
// ---------------------------------------------------------------------------
extern "C" void kernel_launch(void* const* d_in, const int* in_sizes, int n_in,
                              void* d_out, int out_size, void* d_ws,
                              size_t ws_size, hipStream_t stream) {
  const float* x = (const float*)d_in[0];
  const float* wqkv = (const float*)d_in[1];
  const float* wo = (const float*)d_in[2];
  float* out = (float*)d_out;
  char* w = (char*)d_ws;
  const size_t MB = 1024 * 1024;
  ushort* qb  = (ushort*)(w + 0 * MB);
  ushort* kb  = (ushort*)(w + 8 * MB);
  ushort* vb  = (ushort*)(w + 16 * MB);
  ushort* xb  = (ushort*)(w + 24 * MB);
  ushort* wqb = (ushort*)(w + 32 * MB);
  ushort* wob = (ushort*)(w + 38 * MB);
  float2* tab = (float2*)(w + 40 * MB);
  ushort* vtb = (ushort*)(w + 41 * MB);
  ushort* attnb = xb;  // alias: x is dead once QKV GEMM completes

  hipLaunchKernelGGL(rope_table_kernel, dim3(256), dim3(256), 0, stream, tab);
  hipLaunchKernelGGL(cast_all_kernel, dim3(8192), dim3(256), 0, stream,
                     x, wqkv, wo, xb, wqb, wob);
  hipLaunchKernelGGL(qkv_mfma_kernel, dim3(3 * kD / 256, kM / 256), dim3(512),
                     0, stream, xb, wqb, tab, qb, kb, vb);
  hipLaunchKernelGGL(vtrans_kernel, dim3(kS / 64, kB * kH), dim3(256), 0,
                     stream, vb, vtb);
  hipLaunchKernelGGL(attn_mfma_kernel, dim3(512), dim3(256), 0, stream,
                     qb, kb, vtb, attnb);
  hipLaunchKernelGGL(proj_mfma_kernel, dim3(kD / 256, kM / 256), dim3(512), 0,
                     stream, attnb, wob, out);
}

// Round 7
// 176.771 us; speedup vs baseline: 1.0002x; 1.0002x over previous
//
#include <hip/hip_runtime.h>
#include <math.h>

// Problem constants (fixed by the reference).
#define kB 2
#define kS 2048
#define kD 1024
#define kH 16
#define kDk 64
#define kM (kB * kS)  // 4096 rows of x
#define kNT (kD / 64) // 16 K-tiles of BK=64
// log2(10000)
#define kLog2Theta 13.287712379549449
// 0.125 (1/sqrt(dk)) * log2(e): folded into stored Q; softmax in exp2 space
#define C_SCALE 0.18033688011112042f

typedef __attribute__((ext_vector_type(4))) float f32x4;
typedef __attribute__((ext_vector_type(16))) float f32x16;
typedef __attribute__((ext_vector_type(8))) __bf16 bf16x8;

__device__ __forceinline__ ushort f2bf(float f) {
  uint u = __float_as_uint(f);
  return (ushort)((u + 0x7fffu + ((u >> 16) & 1u)) >> 16);  // RNE
}
__device__ __forceinline__ uint cvt_pk_bf16(float lo, float hi) {
  uint r;
  asm("v_cvt_pk_bf16_f32 %0, %1, %2" : "=v"(r) : "v"(lo), "v"(hi));
  return r;
}

typedef __attribute__((address_space(1))) void gvoid;
typedef __attribute__((address_space(3))) void lvoid;
__device__ __forceinline__ void load_lds16(const void* g, void* l) {
  __builtin_amdgcn_global_load_lds((gvoid*)g, (lvoid*)l, 16, 0, 0);
}

// ---------------------------------------------------------------------------
// RoPE cos/sin table: tab[s*32+p] = {cos, sin}(s * theta^(-p/32)). f64 trig.
// ---------------------------------------------------------------------------
__global__ __launch_bounds__(256) void rope_table_kernel(float2* __restrict__ tab) {
  const int i = blockIdx.x * 256 + threadIdx.x;  // 65536 entries
  const int s = i >> 5, p = i & 31;
  const double ang = (double)s * exp2(-(double)p * (kLog2Theta / 32.0));
  tab[i] = make_float2((float)cos(ang), (float)sin(ang));
}

// ---------------------------------------------------------------------------
// All three f32 -> bf16 casts in one launch (RNE), float4 per thread.
// ---------------------------------------------------------------------------
__global__ __launch_bounds__(256) void cast_all_kernel(
    const float* __restrict__ x, const float* __restrict__ wq,
    const float* __restrict__ wo, ushort* __restrict__ xb,
    ushort* __restrict__ wqb, ushort* __restrict__ wob) {
  const int i = blockIdx.x * 256 + threadIdx.x;
  const float* src;
  ushort* dst;
  int off;
  if (i < 1048576) {
    src = x; dst = xb; off = i;
  } else if (i < 1048576 + 786432) {
    src = wq; dst = wqb; off = i - 1048576;
  } else {
    src = wo; dst = wob; off = i - 1835008;
  }
  const float4 v = reinterpret_cast<const float4*>(src)[off];
  ushort4 o;
  o.x = f2bf(v.x); o.y = f2bf(v.y); o.z = f2bf(v.z); o.w = f2bf(v.w);
  reinterpret_cast<ushort4*>(dst)[off] = o;
}

// ---------------------------------------------------------------------------
// V (B,H,S,dk) -> Vt (B,H,dk,S), LDS-tiled 64x64 transpose.
// ---------------------------------------------------------------------------
__global__ __launch_bounds__(256) void vtrans_kernel(
    const ushort* __restrict__ v, ushort* __restrict__ vt) {
  __shared__ ushort T[64 * 66];
  const int bh = blockIdx.y, st = blockIdx.x;
  const int tid = threadIdx.x;
  const ushort* vp = v + ((size_t)bh * kS + st * 64) * kDk;
#pragma unroll
  for (int u = 0; u < 2; ++u) {
    const int idx = u * 256 + tid;
    const int r = idx >> 3, c = (idx & 7) << 3;
    const uint4 d4 = *reinterpret_cast<const uint4*>(&vp[r * 64 + c]);
    uint* dst = reinterpret_cast<uint*>(&T[r * 66 + c]);
    dst[0] = d4.x; dst[1] = d4.y; dst[2] = d4.z; dst[3] = d4.w;
  }
  __syncthreads();
  const int d = tid >> 2, seg = tid & 3;
  ushort tmp[16];
#pragma unroll
  for (int j = 0; j < 16; ++j) tmp[j] = T[(seg * 16 + j) * 66 + d];
  ushort* dst = vt + ((size_t)bh * kDk + d) * kS + st * 64 + seg * 16;
  *reinterpret_cast<uint4*>(dst) = *reinterpret_cast<uint4*>(tmp);
  *reinterpret_cast<uint4*>(dst + 8) = *reinterpret_cast<uint4*>(tmp + 8);
}

// ---------------------------------------------------------------------------
// 256x256 8-wave counted-vmcnt GEMM mainloop (m201-template port).
// C[256x256] = A[256xK] * B[256xK]^T, bf16 K-major inputs.
// 512 thr = 8 waves (2M x 4N), per-wave output 128x64 (8x4 frags of 16x16).
// LDS: 2 K-tile buffers x (A 256x64 + B 256x64) bf16 = 128 KB.
// Per K-tile: 4 quadrant-phases {12 swizzled ds_read_b128 | stage-issue ->
// s_barrier -> lgkmcnt(0) -> setprio(1) 16 MFMA setprio(0) -> s_barrier}.
// All 8 staging loads of tile t+1 issue at phase 0; single vmcnt(0) at end of
// phase 3 (~3 phases after issue — never waits on just-issued loads).
// LDS slot-swizzle slot ^= (row&7): inverse-swizzled global source + swizzled
// frag reads (both-sides, rule #21) -> conflict-free ds_read_b128.
// ---------------------------------------------------------------------------
__device__ __forceinline__ void gemm256_mainloop(
    const ushort* __restrict__ A, const ushort* __restrict__ B,
    int m0, int n0, int tid,
    ushort* As0, ushort* Bs0, ushort* As1, ushort* Bs1,
    f32x4 (&acc)[8][4]) {
  const int lane = tid & 63;
  const int wmi = (tid >> 6) >> 2;   // 0..1 (M wave row)
  const int wni = (tid >> 6) & 3;    // 0..3 (N wave col)
  const int fr = lane & 15, fq = lane >> 4;

  // Stage one full K-tile (A 256x64 + B 256x64) with inverse-swizzled source.
  auto stage_tile = [&](int k0, ushort* Ad, ushort* Bd) {
#pragma unroll
    for (int half = 0; half < 2; ++half)
#pragma unroll
      for (int u = 0; u < 2; ++u) {
        const int c = u * 512 + tid;
        const int r = c >> 3, sl = c & 7;
        const int gcol = k0 + ((sl ^ (r & 7)) << 3);
        const int loff = ((half * 128 + r) << 6) + (sl << 3);
        load_lds16(&A[(size_t)(m0 + half * 128 + r) * kD + gcol], &Ad[loff]);
        load_lds16(&B[(size_t)(n0 + half * 128 + r) * kD + gcol], &Bd[loff]);
      }
  };
  // Swizzled fragment read: logical K-slot (kk*4+fq) at physical ^ (row&7).
  auto frag = [&](const ushort* S, int row, int kk) -> bf16x8 {
    const int off = ((kk << 5) + (fq << 3)) ^ ((fr & 7) << 3);
    return *reinterpret_cast<const bf16x8*>(&S[(row << 6) + off]);
  };

  stage_tile(0, As0, Bs0);
  asm volatile("s_waitcnt vmcnt(0)" ::: "memory");
  __builtin_amdgcn_s_barrier();

  auto tile = [&](int kt, const ushort* cA, const ushort* cB,
                  ushort* nA, ushort* nB) {
#pragma unroll
    for (int p = 0; p < 4; ++p) {
      const int iset = (p & 1) << 2, jset = (p >> 1) << 1;
      bf16x8 af[4][2], bfv[2][2];
#pragma unroll
      for (int i2 = 0; i2 < 4; ++i2)
#pragma unroll
        for (int kk = 0; kk < 2; ++kk)
          af[i2][kk] = frag(cA, (wmi << 7) + (iset + i2) * 16 + fr, kk);
#pragma unroll
      for (int j2 = 0; j2 < 2; ++j2)
#pragma unroll
        for (int kk = 0; kk < 2; ++kk)
          bfv[j2][kk] = frag(cB, (wni << 6) + (jset + j2) * 16 + fr, kk);
      if (p == 0 && kt + 1 < kNT) stage_tile((kt + 1) << 6, nA, nB);
      __builtin_amdgcn_s_barrier();
      asm volatile("s_waitcnt lgkmcnt(0)" ::: "memory");
      __builtin_amdgcn_sched_barrier(0);
      __builtin_amdgcn_s_setprio(1);
#pragma unroll
      for (int i2 = 0; i2 < 4; ++i2)
#pragma unroll
        for (int j2 = 0; j2 < 2; ++j2)
#pragma unroll
          for (int kk = 0; kk < 2; ++kk)
            acc[iset + i2][jset + j2] = __builtin_amdgcn_mfma_f32_16x16x32_bf16(
                af[i2][kk], bfv[j2][kk], acc[iset + i2][jset + j2], 0, 0, 0);
      __builtin_amdgcn_s_setprio(0);
      if (p == 3) asm volatile("s_waitcnt vmcnt(0)" ::: "memory");
      __builtin_amdgcn_s_barrier();
    }
  };

  for (int kt = 0; kt < kNT; kt += 2) {
    tile(kt, As0, Bs0, As1, Bs1);
    tile(kt + 1, As1, Bs1, As0, Bs0);
  }
}

// ---------------------------------------------------------------------------
// QKV projection (256² 8-phase) with fused RoPE epilogue. Q,K,V bf16
// (B,H,S,dk); Q pre-scaled by C_SCALE.
// ---------------------------------------------------------------------------
__global__ __launch_bounds__(512, 2) void qkv_mfma_kernel(
    const ushort* __restrict__ xb, const ushort* __restrict__ wqb,
    const float2* __restrict__ tab,
    ushort* __restrict__ q, ushort* __restrict__ k, ushort* __restrict__ v) {
  __shared__ ushort As0[256 * 64], Bs0[256 * 64];
  __shared__ ushort As1[256 * 64], Bs1[256 * 64];
  const int tid = threadIdx.x;
  const int m0 = blockIdx.y << 8, n0 = blockIdx.x << 8;
  f32x4 acc[8][4];
#pragma unroll
  for (int i = 0; i < 8; ++i)
#pragma unroll
    for (int j = 0; j < 4; ++j) acc[i][j] = {0.f, 0.f, 0.f, 0.f};

  gemm256_mainloop(xb, wqb, m0, n0, tid, As0, Bs0, As1, Bs1, acc);

  const int lane = tid & 63;
  const int wmi = (tid >> 6) >> 2, wni = (tid >> 6) & 3;
  const int fr = lane & 15, fq = lane >> 4;
  const int t = n0 >> 10;  // 0=Q 1=K 2=V (block-uniform: 256 | 1024)
  ushort* dst = (t == 0) ? q : (t == 1) ? k : v;

#pragma unroll
  for (int i = 0; i < 8; ++i) {
    const int mbase = m0 + (wmi << 7) + i * 16 + fq * 4;
#pragma unroll
    for (int j = 0; j < 4; ++j) {
      const int n = n0 + (wni << 6) + j * 16 + fr;
      const int h = (n >> 6) & 15, d = n & 63;
#pragma unroll
      for (int r = 0; r < 4; ++r) {
        const int m = mbase + r;
        const int b = m >> 11, s = m & (kS - 1);
        float val = acc[i][j][r];
        if (t < 2) {  // RoPE: pair exchange with lane^1 (cols d, d^1)
          const float2 cs = tab[(s << 5) + (d >> 1)];
          const float partner = __shfl_xor(val, 1);
          val = (d & 1) ? (partner * cs.y + val * cs.x)
                        : (val * cs.x - partner * cs.y);
        }
        if (t == 0) val *= C_SCALE;  // fold softmax scale into Q
        dst[(((size_t)((b << 4) + h) << 11) + s) * kDk + d] = f2bf(val);
      }
    }
  }
}

// ---------------------------------------------------------------------------
// Output projection (256² 8-phase), f32 store to d_out.
// ---------------------------------------------------------------------------
__global__ __launch_bounds__(512, 2) void proj_mfma_kernel(
    const ushort* __restrict__ ab, const ushort* __restrict__ wob,
    float* __restrict__ out) {
  __shared__ ushort As0[256 * 64], Bs0[256 * 64];
  __shared__ ushort As1[256 * 64], Bs1[256 * 64];
  const int tid = threadIdx.x;
  const int m0 = blockIdx.y << 8, n0 = blockIdx.x << 8;
  f32x4 acc[8][4];
#pragma unroll
  for (int i = 0; i < 8; ++i)
#pragma unroll
    for (int j = 0; j < 4; ++j) acc[i][j] = {0.f, 0.f, 0.f, 0.f};

  gemm256_mainloop(ab, wob, m0, n0, tid, As0, Bs0, As1, Bs1, acc);

  const int lane = tid & 63;
  const int wmi = (tid >> 6) >> 2, wni = (tid >> 6) & 3;
  const int fr = lane & 15, fq = lane >> 4;
#pragma unroll
  for (int i = 0; i < 8; ++i)
#pragma unroll
    for (int j = 0; j < 4; ++j)
#pragma unroll
      for (int r = 0; r < 4; ++r)
        out[(size_t)(m0 + (wmi << 7) + i * 16 + fq * 4 + r) * kD +
            n0 + (wni << 6) + j * 16 + fr] = acc[i][j][r];
}

// ---------------------------------------------------------------------------
// Causal flash attention, bf16 MFMA 32x32x16, swapped operands, KVBLK=128,
// double-buffered LDS (64KB), static-max softmax (scores are O(1e-2): fixed
// max is exact; no rescale, no max tracking).
// ---------------------------------------------------------------------------
__global__ __launch_bounds__(256) void attn_mfma_kernel(
    const ushort* __restrict__ q, const ushort* __restrict__ k,
    const ushort* __restrict__ vt, ushort* __restrict__ ob) {
  __shared__ ushort smem[32768];  // 64KB: buf{0,1} x (Ks[128][64] | Vts[64][128])
  const int tid = threadIdx.x;
  const int lane = tid & 63;
  const int wq = tid >> 6;             // wave 0..3
  const int l5 = lane >> 5;
  const int ln = lane & 31;            // q column owned by this lane
  const int swz = (ln & 7) << 4;       // LDS byte swizzle for frag reads

  // Balanced (qi, bh) mapping: grp<8 -> qi 15..8, grp>=8 -> qi 0..7.
  const int idx = blockIdx.x;
  const int grp = idx >> 5, bh = idx & 31;
  const int qi = (grp < 8) ? (15 - grp) : (grp - 8);
  const int qb = qi << 7;
  const int nt = qi + 1;               // 128-key tiles

  const ushort* qp = q + (size_t)bh * kS * kDk;
  const ushort* kp = k + (size_t)bh * kS * kDk;
  const ushort* vp = vt + (size_t)bh * kDk * kS;  // [d][s]

  // Q fragments (B-operand, persist): dk = kk*16 + l5*8 + j. Q pre-scaled.
  bf16x8 bq[4];
#pragma unroll
  for (int kk = 0; kk < 4; ++kk)
    bq[kk] = *reinterpret_cast<const bf16x8*>(
        &qp[(size_t)(qb + wq * 32 + ln) * kDk + kk * 16 + l5 * 8]);

  f32x16 acc_o[2];
#pragma unroll
  for (int db = 0; db < 2; ++db)
#pragma unroll
    for (int r = 0; r < 16; ++r) acc_o[db][r] = 0.f;
  float l_run = 0.f;

  auto stage = [&](int kt, int buf) {
    ushort* Kd = smem + buf * 16384;
    ushort* Vd = Kd + 8192;
#pragma unroll
    for (int u = 0; u < 4; ++u) {
      const int c = u * 256 + tid;
      {
        const int r = c >> 3, sl = c & 7;
        load_lds16(&kp[(size_t)(kt * 128 + r) * kDk + ((sl ^ (r & 7)) << 3)],
                   &Kd[c << 3]);
      }
      {
        const int r = c >> 4, sl = c & 15;
        load_lds16(&vp[(size_t)r * kS + kt * 128 + ((sl ^ (r & 7)) << 3)],
                   &Vd[c << 3]);
      }
    }
  };

  stage(0, 0);

  for (int kt = 0; kt < nt; ++kt) {
    const int cur = kt & 1;
    __syncthreads();                   // buf[cur] ready (vmcnt drained here)
    if (kt + 1 < nt) stage(kt + 1, cur ^ 1);  // prefetch flies under compute

    const char* KsB = reinterpret_cast<const char*>(smem + cur * 16384);
    const char* VtsB = KsB + 16384;

    // ---- QK^T: 4 key-blocks of 32 ----
    f32x16 accs[4];
    __builtin_amdgcn_s_setprio(1);
#pragma unroll
    for (int cb = 0; cb < 4; ++cb) {
#pragma unroll
      for (int r = 0; r < 16; ++r) accs[cb][r] = 0.f;
#pragma unroll
      for (int kk = 0; kk < 4; ++kk) {
        const bf16x8 av = *reinterpret_cast<const bf16x8*>(
            KsB + (cb * 32 + ln) * 128 + ((kk * 32 + l5 * 16) ^ swz));
        accs[cb] = __builtin_amdgcn_mfma_f32_32x32x16_bf16(av, bq[kk], accs[cb], 0, 0, 0);
      }
    }
    __builtin_amdgcn_s_setprio(0);

    // ---- causal mask (diagonal tile only) ----
    if (kt == qi) {
      const int lim = (wq << 5) + ln;  // qrow - qb
#pragma unroll
      for (int cb = 0; cb < 4; ++cb)
#pragma unroll
        for (int r = 0; r < 16; ++r) {
          const int key = cb * 32 + (r & 3) + 8 * (r >> 2) + 4 * l5;
          if (key > lim) accs[cb][r] = -INFINITY;
        }
    }

    // ---- static-max softmax: p = exp2(s), accumulate l ----
    uint c8[4][8];
    float lsum = 0.f;
#pragma unroll
    for (int cb = 0; cb < 4; ++cb) {
      float s0 = 0.f, s1 = 0.f, s2 = 0.f, s3 = 0.f;
      float p[16];
#pragma unroll
      for (int r = 0; r < 16; ++r) {
        p[r] = exp2f(accs[cb][r]);
        if ((r & 3) == 0) s0 += p[r];
        else if ((r & 3) == 1) s1 += p[r];
        else if ((r & 3) == 2) s2 += p[r];
        else s3 += p[r];
      }
      lsum += (s0 + s1) + (s2 + s3);
#pragma unroll
      for (int t = 0; t < 8; ++t)
        c8[cb][t] = cvt_pk_bf16(p[2 * t], p[2 * t + 1]);
    }
    l_run += lsum;

    // ---- PV: for each 16-key slab, build P B-frag and MFMA ----
    __builtin_amdgcn_s_setprio(1);
#pragma unroll
    for (int kb = 0; kb < 8; ++kb) {
      const int cb = kb >> 1, base = (kb & 1) * 4;
      const uint a0 = c8[cb][base + 0], a1 = c8[cb][base + 1];
      const uint b0 = c8[cb][base + 2], b1 = c8[cb][base + 3];
      const uint sa0 = (uint)__shfl_xor((int)a0, 32);
      const uint sa1 = (uint)__shfl_xor((int)a1, 32);
      const uint sb0 = (uint)__shfl_xor((int)b0, 32);
      const uint sb1 = (uint)__shfl_xor((int)b1, 32);
      uint4 dw;
      dw.x = l5 ? sb0 : a0;
      dw.y = l5 ? sb1 : a1;
      dw.z = l5 ? b0 : sa0;
      dw.w = l5 ? b1 : sa1;
      const bf16x8 pa = *reinterpret_cast<const bf16x8*>(&dw);
#pragma unroll
      for (int db = 0; db < 2; ++db) {
        const bf16x8 av = *reinterpret_cast<const bf16x8*>(
            VtsB + (db * 32 + ln) * 256 + ((kb * 32 + l5 * 16) ^ swz));
        acc_o[db] = __builtin_amdgcn_mfma_f32_32x32x16_bf16(av, pa, acc_o[db], 0, 0, 0);
      }
    }
    __builtin_amdgcn_s_setprio(0);
  }

  // ---- combine the two half-wave l partials, normalize, store ----
  const float l_tot = l_run + __shfl_xor(l_run, 32);
  const float linv = 1.f / l_tot;

  __syncthreads();                     // all waves done with K/Vt buffers
  char* OsB = reinterpret_cast<char*>(smem);  // Os: [128 q][64 d], swizzled
  const int orow = wq * 32 + ln;
#pragma unroll
  for (int db = 0; db < 2; ++db)
#pragma unroll
    for (int t = 0; t < 8; ++t) {
      const int reg = 2 * t;
      const int d = db * 32 + (reg & 3) + 8 * (reg >> 2) + 4 * l5;
      const uint pk2 = cvt_pk_bf16(acc_o[db][reg] * linv, acc_o[db][reg + 1] * linv);
      *reinterpret_cast<uint*>(OsB + orow * 128 + ((d * 2) ^ swz)) = pk2;
    }
  __syncthreads();
  const int b = bh >> 4, h = bh & 15;
  const int qrw = tid >> 1, half = tid & 1;
  ushort* orow_g = ob + ((size_t)(b * kS + qb + qrw)) * kD + h * kDk + half * 32;
#pragma unroll
  for (int sl = 0; sl < 4; ++sl) {
    const uint4 vdat = *reinterpret_cast<const uint4*>(
        OsB + qrw * 128 + ((half * 64 + sl * 16) ^ ((qrw & 7) << 4)));
    *reinterpret_cast<uint4*>(orow_g + sl * 8) = vdat;
  }
}

// ---------------------------------------------------------------------------
// Workspace (bytes from d_ws base), total 49 MB:
//   qb 0..8M, kb 8..16M, vb 16..24M (bf16, (B,H,S,dk))
//   xb 24..32M (x bf16; aliased as attnb after QKV GEMM)
//   wqb 32..38M, wob 38..40M, tab 40..40.5M, vtb 41..49M (Vt (B,H,dk,S))
// ---------------------------------------------------------------------------
extern "C" void kernel_launch(void* const* d_in, const int* in_sizes, int n_in,
                              void* d_out, int out_size, void* d_ws,
                              size_t ws_size, hipStream_t stream) {
  const float* x = (const float*)d_in[0];
  const float* wqkv = (const float*)d_in[1];
  const float* wo = (const float*)d_in[2];
  float* out = (float*)d_out;
  char* w = (char*)d_ws;
  const size_t MB = 1024 * 1024;
  ushort* qb  = (ushort*)(w + 0 * MB);
  ushort* kb  = (ushort*)(w + 8 * MB);
  ushort* vb  = (ushort*)(w + 16 * MB);
  ushort* xb  = (ushort*)(w + 24 * MB);
  ushort* wqb = (ushort*)(w + 32 * MB);
  ushort* wob = (ushort*)(w + 38 * MB);
  float2* tab = (float2*)(w + 40 * MB);
  ushort* vtb = (ushort*)(w + 41 * MB);
  ushort* attnb = xb;  // alias: x is dead once QKV GEMM completes

  hipLaunchKernelGGL(rope_table_kernel, dim3(256), dim3(256), 0, stream, tab);
  hipLaunchKernelGGL(cast_all_kernel, dim3(8192), dim3(256), 0, stream,
                     x, wqkv, wo, xb, wqb, wob);
  hipLaunchKernelGGL(qkv_mfma_kernel, dim3(3 * kD / 256, kM / 256), dim3(512),
                     0, stream, xb, wqb, tab, qb, kb, vb);
  hipLaunchKernelGGL(vtrans_kernel, dim3(kS / 64, kB * kH), dim3(256), 0,
                     stream, vb, vtb);
  hipLaunchKernelGGL(attn_mfma_kernel, dim3(512), dim3(256), 0, stream,
                     qb, kb, vtb, attnb);
  hipLaunchKernelGGL(proj_mfma_kernel, dim3(kD / 256, kM / 256), dim3(512), 0,
                     stream, attnb, wob, out);
}

// Round 8
// 176.708 us; speedup vs baseline: 1.0006x; 1.0004x over previous
//
#include <hip/hip_runtime.h>
#include <math.h>

// Problem constants (fixed by the reference).
#define kB 2
#define kS 2048
#define kD 1024
#define kH 16
#define kDk 64
#define kM (kB * kS)  // 4096 rows of x
#define kNT (kD / 64) // 16 K-tiles of BK=64
// log2(10000)
#define kLog2Theta 13.287712379549449
// 0.125 (1/sqrt(dk)) * log2(e): folded into stored Q; softmax in exp2 space
#define C_SCALE 0.18033688011112042f

typedef __attribute__((ext_vector_type(4))) float f32x4;
typedef __attribute__((ext_vector_type(16))) float f32x16;
typedef __attribute__((ext_vector_type(8))) __bf16 bf16x8;

__device__ __forceinline__ ushort f2bf(float f) {
  uint u = __float_as_uint(f);
  return (ushort)((u + 0x7fffu + ((u >> 16) & 1u)) >> 16);  // RNE
}
__device__ __forceinline__ uint cvt_pk_bf16(float lo, float hi) {
  uint r;
  asm("v_cvt_pk_bf16_f32 %0, %1, %2" : "=v"(r) : "v"(lo), "v"(hi));
  return r;
}

typedef __attribute__((address_space(1))) void gvoid;
typedef __attribute__((address_space(3))) void lvoid;
__device__ __forceinline__ void load_lds16(const void* g, void* l) {
  __builtin_amdgcn_global_load_lds((gvoid*)g, (lvoid*)l, 16, 0, 0);
}

// ---------------------------------------------------------------------------
// RoPE cos/sin table: tab[s*32+p] = {cos, sin}(s * theta^(-p/32)). f64 trig.
// ---------------------------------------------------------------------------
__global__ __launch_bounds__(256) void rope_table_kernel(float2* __restrict__ tab) {
  const int i = blockIdx.x * 256 + threadIdx.x;  // 65536 entries
  const int s = i >> 5, p = i & 31;
  const double ang = (double)s * exp2(-(double)p * (kLog2Theta / 32.0));
  tab[i] = make_float2((float)cos(ang), (float)sin(ang));
}

// ---------------------------------------------------------------------------
// All three f32 -> bf16 casts in one launch (RNE), float4 per thread.
// ---------------------------------------------------------------------------
__global__ __launch_bounds__(256) void cast_all_kernel(
    const float* __restrict__ x, const float* __restrict__ wq,
    const float* __restrict__ wo, ushort* __restrict__ xb,
    ushort* __restrict__ wqb, ushort* __restrict__ wob) {
  const int i = blockIdx.x * 256 + threadIdx.x;
  const float* src;
  ushort* dst;
  int off;
  if (i < 1048576) {
    src = x; dst = xb; off = i;
  } else if (i < 1048576 + 786432) {
    src = wq; dst = wqb; off = i - 1048576;
  } else {
    src = wo; dst = wob; off = i - 1835008;
  }
  const float4 v = reinterpret_cast<const float4*>(src)[off];
  ushort4 o;
  o.x = f2bf(v.x); o.y = f2bf(v.y); o.z = f2bf(v.z); o.w = f2bf(v.w);
  reinterpret_cast<ushort4*>(dst)[off] = o;
}

// ---------------------------------------------------------------------------
// V (B,H,S,dk) -> Vt (B,H,dk,S), LDS-tiled 64x64 transpose.
// ---------------------------------------------------------------------------
__global__ __launch_bounds__(256) void vtrans_kernel(
    const ushort* __restrict__ v, ushort* __restrict__ vt) {
  __shared__ ushort T[64 * 66];
  const int bh = blockIdx.y, st = blockIdx.x;
  const int tid = threadIdx.x;
  const ushort* vp = v + ((size_t)bh * kS + st * 64) * kDk;
#pragma unroll
  for (int u = 0; u < 2; ++u) {
    const int idx = u * 256 + tid;
    const int r = idx >> 3, c = (idx & 7) << 3;
    const uint4 d4 = *reinterpret_cast<const uint4*>(&vp[r * 64 + c]);
    uint* dst = reinterpret_cast<uint*>(&T[r * 66 + c]);
    dst[0] = d4.x; dst[1] = d4.y; dst[2] = d4.z; dst[3] = d4.w;
  }
  __syncthreads();
  const int d = tid >> 2, seg = tid & 3;
  ushort tmp[16];
#pragma unroll
  for (int j = 0; j < 16; ++j) tmp[j] = T[(seg * 16 + j) * 66 + d];
  ushort* dst = vt + ((size_t)bh * kDk + d) * kS + st * 64 + seg * 16;
  *reinterpret_cast<uint4*>(dst) = *reinterpret_cast<uint4*>(tmp);
  *reinterpret_cast<uint4*>(dst + 8) = *reinterpret_cast<uint4*>(tmp + 8);
}

// ---------------------------------------------------------------------------
// 256x256 8-wave counted-vmcnt GEMM mainloop (m201-template port).
// C[256x256] = A[256xK] * B[256xK]^T, bf16 K-major inputs.
// 512 thr = 8 waves (2M x 4N), per-wave output 128x64 (8x4 frags of 16x16).
// LDS: 2 K-tile buffers x (A 256x64 + B 256x64) bf16 = 128 KB.
// Per K-tile: 4 quadrant-phases {12 swizzled ds_read_b128 | stage-issue ->
// s_barrier -> lgkmcnt(0) -> setprio(1) 16 MFMA setprio(0) -> s_barrier}.
// All 8 staging loads of tile t+1 issue at phase 0; single vmcnt(0) at end of
// phase 3 (~3 phases after issue — never waits on just-issued loads).
// LDS slot-swizzle slot ^= (row&7): inverse-swizzled global source + swizzled
// frag reads (both-sides, rule #21) -> conflict-free ds_read_b128.
// ---------------------------------------------------------------------------
__device__ __forceinline__ void gemm256_mainloop(
    const ushort* __restrict__ A, const ushort* __restrict__ B,
    int m0, int n0, int tid,
    ushort* As0, ushort* Bs0, ushort* As1, ushort* Bs1,
    f32x4 (&acc)[8][4]) {
  const int lane = tid & 63;
  const int wmi = (tid >> 6) >> 2;   // 0..1 (M wave row)
  const int wni = (tid >> 6) & 3;    // 0..3 (N wave col)
  const int fr = lane & 15, fq = lane >> 4;

  // Stage one full K-tile (A 256x64 + B 256x64) with inverse-swizzled source.
  auto stage_tile = [&](int k0, ushort* Ad, ushort* Bd) {
#pragma unroll
    for (int half = 0; half < 2; ++half)
#pragma unroll
      for (int u = 0; u < 2; ++u) {
        const int c = u * 512 + tid;
        const int r = c >> 3, sl = c & 7;
        const int gcol = k0 + ((sl ^ (r & 7)) << 3);
        const int loff = ((half * 128 + r) << 6) + (sl << 3);
        load_lds16(&A[(size_t)(m0 + half * 128 + r) * kD + gcol], &Ad[loff]);
        load_lds16(&B[(size_t)(n0 + half * 128 + r) * kD + gcol], &Bd[loff]);
      }
  };
  // Swizzled fragment read: logical K-slot (kk*4+fq) at physical ^ (row&7).
  auto frag = [&](const ushort* S, int row, int kk) -> bf16x8 {
    const int off = ((kk << 5) + (fq << 3)) ^ ((fr & 7) << 3);
    return *reinterpret_cast<const bf16x8*>(&S[(row << 6) + off]);
  };

  stage_tile(0, As0, Bs0);
  asm volatile("s_waitcnt vmcnt(0)" ::: "memory");
  __builtin_amdgcn_s_barrier();

  auto tile = [&](int kt, const ushort* cA, const ushort* cB,
                  ushort* nA, ushort* nB) {
#pragma unroll
    for (int p = 0; p < 4; ++p) {
      const int iset = (p & 1) << 2, jset = (p >> 1) << 1;
      bf16x8 af[4][2], bfv[2][2];
#pragma unroll
      for (int i2 = 0; i2 < 4; ++i2)
#pragma unroll
        for (int kk = 0; kk < 2; ++kk)
          af[i2][kk] = frag(cA, (wmi << 7) + (iset + i2) * 16 + fr, kk);
#pragma unroll
      for (int j2 = 0; j2 < 2; ++j2)
#pragma unroll
        for (int kk = 0; kk < 2; ++kk)
          bfv[j2][kk] = frag(cB, (wni << 6) + (jset + j2) * 16 + fr, kk);
      if (p == 0 && kt + 1 < kNT) stage_tile((kt + 1) << 6, nA, nB);
      __builtin_amdgcn_s_barrier();
      asm volatile("s_waitcnt lgkmcnt(0)" ::: "memory");
      __builtin_amdgcn_sched_barrier(0);
      __builtin_amdgcn_s_setprio(1);
#pragma unroll
      for (int i2 = 0; i2 < 4; ++i2)
#pragma unroll
        for (int j2 = 0; j2 < 2; ++j2)
#pragma unroll
          for (int kk = 0; kk < 2; ++kk)
            acc[iset + i2][jset + j2] = __builtin_amdgcn_mfma_f32_16x16x32_bf16(
                af[i2][kk], bfv[j2][kk], acc[iset + i2][jset + j2], 0, 0, 0);
      __builtin_amdgcn_s_setprio(0);
      if (p == 3) asm volatile("s_waitcnt vmcnt(0)" ::: "memory");
      __builtin_amdgcn_s_barrier();
    }
  };

  for (int kt = 0; kt < kNT; kt += 2) {
    tile(kt, As0, Bs0, As1, Bs1);
    tile(kt + 1, As1, Bs1, As0, Bs0);
  }
}

// ---------------------------------------------------------------------------
// QKV projection (256² 8-phase) with fused RoPE epilogue. Q,K,V bf16
// (B,H,S,dk); Q pre-scaled by C_SCALE.
// ---------------------------------------------------------------------------
__global__ __launch_bounds__(512, 2) void qkv_mfma_kernel(
    const ushort* __restrict__ xb, const ushort* __restrict__ wqb,
    const float2* __restrict__ tab,
    ushort* __restrict__ q, ushort* __restrict__ k, ushort* __restrict__ v) {
  __shared__ ushort As0[256 * 64], Bs0[256 * 64];
  __shared__ ushort As1[256 * 64], Bs1[256 * 64];
  const int tid = threadIdx.x;
  const int m0 = blockIdx.y << 8, n0 = blockIdx.x << 8;
  f32x4 acc[8][4];
#pragma unroll
  for (int i = 0; i < 8; ++i)
#pragma unroll
    for (int j = 0; j < 4; ++j) acc[i][j] = {0.f, 0.f, 0.f, 0.f};

  gemm256_mainloop(xb, wqb, m0, n0, tid, As0, Bs0, As1, Bs1, acc);

  const int lane = tid & 63;
  const int wmi = (tid >> 6) >> 2, wni = (tid >> 6) & 3;
  const int fr = lane & 15, fq = lane >> 4;
  const int t = n0 >> 10;  // 0=Q 1=K 2=V (block-uniform: 256 | 1024)
  ushort* dst = (t == 0) ? q : (t == 1) ? k : v;

#pragma unroll
  for (int i = 0; i < 8; ++i) {
    const int mbase = m0 + (wmi << 7) + i * 16 + fq * 4;
#pragma unroll
    for (int j = 0; j < 4; ++j) {
      const int n = n0 + (wni << 6) + j * 16 + fr;
      const int h = (n >> 6) & 15, d = n & 63;
#pragma unroll
      for (int r = 0; r < 4; ++r) {
        const int m = mbase + r;
        const int b = m >> 11, s = m & (kS - 1);
        float val = acc[i][j][r];
        if (t < 2) {  // RoPE: pair exchange with lane^1 (cols d, d^1)
          const float2 cs = tab[(s << 5) + (d >> 1)];
          const float partner = __shfl_xor(val, 1);
          val = (d & 1) ? (partner * cs.y + val * cs.x)
                        : (val * cs.x - partner * cs.y);
        }
        if (t == 0) val *= C_SCALE;  // fold softmax scale into Q
        dst[(((size_t)((b << 4) + h) << 11) + s) * kDk + d] = f2bf(val);
      }
    }
  }
}

// ---------------------------------------------------------------------------
// Output projection (256² 8-phase), f32 store to d_out.
// ---------------------------------------------------------------------------
__global__ __launch_bounds__(512, 2) void proj_mfma_kernel(
    const ushort* __restrict__ ab, const ushort* __restrict__ wob,
    float* __restrict__ out) {
  __shared__ ushort As0[256 * 64], Bs0[256 * 64];
  __shared__ ushort As1[256 * 64], Bs1[256 * 64];
  const int tid = threadIdx.x;
  const int m0 = blockIdx.y << 8, n0 = blockIdx.x << 8;
  f32x4 acc[8][4];
#pragma unroll
  for (int i = 0; i < 8; ++i)
#pragma unroll
    for (int j = 0; j < 4; ++j) acc[i][j] = {0.f, 0.f, 0.f, 0.f};

  gemm256_mainloop(ab, wob, m0, n0, tid, As0, Bs0, As1, Bs1, acc);

  const int lane = tid & 63;
  const int wmi = (tid >> 6) >> 2, wni = (tid >> 6) & 3;
  const int fr = lane & 15, fq = lane >> 4;
#pragma unroll
  for (int i = 0; i < 8; ++i)
#pragma unroll
    for (int j = 0; j < 4; ++j)
#pragma unroll
      for (int r = 0; r < 4; ++r)
        out[(size_t)(m0 + (wmi << 7) + i * 16 + fq * 4 + r) * kD +
            n0 + (wni << 6) + j * 16 + fr] = acc[i][j][r];
}

// ---------------------------------------------------------------------------
// Causal flash attention, bf16 MFMA 32x32x16, swapped operands, KVBLK=128,
// double-buffered LDS (64KB), static-max softmax (scores are O(1e-2): fixed
// max is exact; no rescale, no max tracking).
// ---------------------------------------------------------------------------
__global__ __launch_bounds__(256) void attn_mfma_kernel(
    const ushort* __restrict__ q, const ushort* __restrict__ k,
    const ushort* __restrict__ vt, ushort* __restrict__ ob) {
  __shared__ ushort smem[32768];  // 64KB: buf{0,1} x (Ks[128][64] | Vts[64][128])
  const int tid = threadIdx.x;
  const int lane = tid & 63;
  const int wq = tid >> 6;             // wave 0..3
  const int l5 = lane >> 5;
  const int ln = lane & 31;            // q column owned by this lane
  const int swz = (ln & 7) << 4;       // LDS byte swizzle for frag reads

  // Balanced (qi, bh) mapping: grp<8 -> qi 15..8, grp>=8 -> qi 0..7.
  const int idx = blockIdx.x;
  const int grp = idx >> 5, bh = idx & 31;
  const int qi = (grp < 8) ? (15 - grp) : (grp - 8);
  const int qb = qi << 7;
  const int nt = qi + 1;               // 128-key tiles

  const ushort* qp = q + (size_t)bh * kS * kDk;
  const ushort* kp = k + (size_t)bh * kS * kDk;
  const ushort* vp = vt + (size_t)bh * kDk * kS;  // [d][s]

  // Q fragments (B-operand, persist): dk = kk*16 + l5*8 + j. Q pre-scaled.
  bf16x8 bq[4];
#pragma unroll
  for (int kk = 0; kk < 4; ++kk)
    bq[kk] = *reinterpret_cast<const bf16x8*>(
        &qp[(size_t)(qb + wq * 32 + ln) * kDk + kk * 16 + l5 * 8]);

  f32x16 acc_o[2];
#pragma unroll
  for (int db = 0; db < 2; ++db)
#pragma unroll
    for (int r = 0; r < 16; ++r) acc_o[db][r] = 0.f;
  float l_run = 0.f;

  auto stage = [&](int kt, int buf) {
    ushort* Kd = smem + buf * 16384;
    ushort* Vd = Kd + 8192;
#pragma unroll
    for (int u = 0; u < 4; ++u) {
      const int c = u * 256 + tid;
      {
        const int r = c >> 3, sl = c & 7;
        load_lds16(&kp[(size_t)(kt * 128 + r) * kDk + ((sl ^ (r & 7)) << 3)],
                   &Kd[c << 3]);
      }
      {
        const int r = c >> 4, sl = c & 15;
        load_lds16(&vp[(size_t)r * kS + kt * 128 + ((sl ^ (r & 7)) << 3)],
                   &Vd[c << 3]);
      }
    }
  };

  stage(0, 0);

  for (int kt = 0; kt < nt; ++kt) {
    const int cur = kt & 1;
    __syncthreads();                   // buf[cur] ready (vmcnt drained here)
    if (kt + 1 < nt) stage(kt + 1, cur ^ 1);  // prefetch flies under compute

    const char* KsB = reinterpret_cast<const char*>(smem + cur * 16384);
    const char* VtsB = KsB + 16384;

    // ---- QK^T: 4 key-blocks of 32 ----
    f32x16 accs[4];
    __builtin_amdgcn_s_setprio(1);
#pragma unroll
    for (int cb = 0; cb < 4; ++cb) {
#pragma unroll
      for (int r = 0; r < 16; ++r) accs[cb][r] = 0.f;
#pragma unroll
      for (int kk = 0; kk < 4; ++kk) {
        const bf16x8 av = *reinterpret_cast<const bf16x8*>(
            KsB + (cb * 32 + ln) * 128 + ((kk * 32 + l5 * 16) ^ swz));
        accs[cb] = __builtin_amdgcn_mfma_f32_32x32x16_bf16(av, bq[kk], accs[cb], 0, 0, 0);
      }
    }
    __builtin_amdgcn_s_setprio(0);

    // ---- causal mask (diagonal tile only) ----
    if (kt == qi) {
      const int lim = (wq << 5) + ln;  // qrow - qb
#pragma unroll
      for (int cb = 0; cb < 4; ++cb)
#pragma unroll
        for (int r = 0; r < 16; ++r) {
          const int key = cb * 32 + (r & 3) + 8 * (r >> 2) + 4 * l5;
          if (key > lim) accs[cb][r] = -INFINITY;
        }
    }

    // ---- static-max softmax: p = exp2(s), accumulate l ----
    uint c8[4][8];
    float lsum = 0.f;
#pragma unroll
    for (int cb = 0; cb < 4; ++cb) {
      float s0 = 0.f, s1 = 0.f, s2 = 0.f, s3 = 0.f;
      float p[16];
#pragma unroll
      for (int r = 0; r < 16; ++r) {
        p[r] = exp2f(accs[cb][r]);
        if ((r & 3) == 0) s0 += p[r];
        else if ((r & 3) == 1) s1 += p[r];
        else if ((r & 3) == 2) s2 += p[r];
        else s3 += p[r];
      }
      lsum += (s0 + s1) + (s2 + s3);
#pragma unroll
      for (int t = 0; t < 8; ++t)
        c8[cb][t] = cvt_pk_bf16(p[2 * t], p[2 * t + 1]);
    }
    l_run += lsum;

    // ---- PV: for each 16-key slab, build P B-frag and MFMA ----
    __builtin_amdgcn_s_setprio(1);
#pragma unroll
    for (int kb = 0; kb < 8; ++kb) {
      const int cb = kb >> 1, base = (kb & 1) * 4;
      const uint a0 = c8[cb][base + 0], a1 = c8[cb][base + 1];
      const uint b0 = c8[cb][base + 2], b1 = c8[cb][base + 3];
      const uint sa0 = (uint)__shfl_xor((int)a0, 32);
      const uint sa1 = (uint)__shfl_xor((int)a1, 32);
      const uint sb0 = (uint)__shfl_xor((int)b0, 32);
      const uint sb1 = (uint)__shfl_xor((int)b1, 32);
      uint4 dw;
      dw.x = l5 ? sb0 : a0;
      dw.y = l5 ? sb1 : a1;
      dw.z = l5 ? b0 : sa0;
      dw.w = l5 ? b1 : sa1;
      const bf16x8 pa = *reinterpret_cast<const bf16x8*>(&dw);
#pragma unroll
      for (int db = 0; db < 2; ++db) {
        const bf16x8 av = *reinterpret_cast<const bf16x8*>(
            VtsB + (db * 32 + ln) * 256 + ((kb * 32 + l5 * 16) ^ swz));
        acc_o[db] = __builtin_amdgcn_mfma_f32_32x32x16_bf16(av, pa, acc_o[db], 0, 0, 0);
      }
    }
    __builtin_amdgcn_s_setprio(0);
  }

  // ---- combine the two half-wave l partials, normalize, store ----
  const float l_tot = l_run + __shfl_xor(l_run, 32);
  const float linv = 1.f / l_tot;

  __syncthreads();                     // all waves done with K/Vt buffers
  char* OsB = reinterpret_cast<char*>(smem);  // Os: [128 q][64 d], swizzled
  const int orow = wq * 32 + ln;
#pragma unroll
  for (int db = 0; db < 2; ++db)
#pragma unroll
    for (int t = 0; t < 8; ++t) {
      const int reg = 2 * t;
      const int d = db * 32 + (reg & 3) + 8 * (reg >> 2) + 4 * l5;
      const uint pk2 = cvt_pk_bf16(acc_o[db][reg] * linv, acc_o[db][reg + 1] * linv);
      *reinterpret_cast<uint*>(OsB + orow * 128 + ((d * 2) ^ swz)) = pk2;
    }
  __syncthreads();
  const int b = bh >> 4, h = bh & 15;
  const int qrw = tid >> 1, half = tid & 1;
  ushort* orow_g = ob + ((size_t)(b * kS + qb + qrw)) * kD + h * kDk + half * 32;
#pragma unroll
  for (int sl = 0; sl < 4; ++sl) {
    const uint4 vdat = *reinterpret_cast<const uint4*>(
        OsB + qrw * 128 + ((half * 64 + sl * 16) ^ ((qrw & 7) << 4)));
    *reinterpret_cast<uint4*>(orow_g + sl * 8) = vdat;
  }
}

// ---------------------------------------------------------------------------
// Workspace (bytes from d_ws base), total 49 MB:
//   qb 0..8M, kb 8..16M, vb 16..24M (bf16, (B,H,S,dk))
//   xb 24..32M (x bf16; aliased as attnb after QKV GEMM)
//   wqb 32..38M, wob 38..40M, tab 40..40.5M, vtb 41..49M (Vt (B,H,dk,S))
// ---------------------------------------------------------------------------
extern "C" void kernel_launch(void* const* d_in, const int* in_sizes, int n_in,
                              void* d_out, int out_size, void* d_ws,
                              size_t ws_size, hipStream_t stream) {
  const float* x = (const float*)d_in[0];
  const float* wqkv = (const float*)d_in[1];
  const float* wo = (const float*)d_in[2];
  float* out = (float*)d_out;
  char* w = (char*)d_ws;
  const size_t MB = 1024 * 1024;
  ushort* qb  = (ushort*)(w + 0 * MB);
  ushort* kb  = (ushort*)(w + 8 * MB);
  ushort* vb  = (ushort*)(w + 16 * MB);
  ushort* xb  = (ushort*)(w + 24 * MB);
  ushort* wqb = (ushort*)(w + 32 * MB);
  ushort* wob = (ushort*)(w + 38 * MB);
  float2* tab = (float2*)(w + 40 * MB);
  ushort* vtb = (ushort*)(w + 41 * MB);
  ushort* attnb = xb;  // alias: x is dead once QKV GEMM completes

  hipLaunchKernelGGL(rope_table_kernel, dim3(256), dim3(256), 0, stream, tab);
  hipLaunchKernelGGL(cast_all_kernel, dim3(8192), dim3(256), 0, stream,
                     x, wqkv, wo, xb, wqb, wob);
  hipLaunchKernelGGL(qkv_mfma_kernel, dim3(3 * kD / 256, kM / 256), dim3(512),
                     0, stream, xb, wqb, tab, qb, kb, vb);
  hipLaunchKernelGGL(vtrans_kernel, dim3(kS / 64, kB * kH), dim3(256), 0,
                     stream, vb, vtb);
  hipLaunchKernelGGL(attn_mfma_kernel, dim3(512), dim3(256), 0, stream,
                     qb, kb, vtb, attnb);
  hipLaunchKernelGGL(proj_mfma_kernel, dim3(kD / 256, kM / 256), dim3(512), 0,
                     stream, attnb, wob, out);
}